// Round 13
// baseline (428.715 us; speedup 1.0000x reference)
//
#include <hip/hip_runtime.h>

// Shapes: B=2, L=2048, D_MODEL=1024, H=16, D_K=64
// Pipeline (R13 = R12 but with TWO cross-wave Newton iters — R8-validated envelope):
//  0) pack_mask: mask int32 [B][L][L] -> Mp[b][qt][w][c][8] u32 (wave-contiguous).
//  1) gemm_proj<0/1>: Q/K proj; epilogue writes FRAGMENT-PACKED
//     Qp/Kp[bh][tile][half][c][g][8 f16]  (1 KB contiguous per wave-load).
//  2) gemm_proj<2>: V proj; epilogue writes Vp[bh][tile][nd][c][g][4 f16].
//  3) attn_entmax: 16 q x 2048 k, 8 waves, XCD-swizzled grid, coalesced loads.
//     Swapped QK^T -> f16x2 scores (cvt_pkrtz + fused pk_max tracking);
//     TWO cross-wave Newton iters (packed f16 scans, v_pk_* guaranteed) from
//     tau0=zmax-1 (monotone from below), filter at tau2-0.02 into f32 buckets
//     (CAP=512, stride 513), quarter-wave f32 solve (4 Newton + 3 exact
//     support refines), P in packed f16 -> PV from regs (16x16x16 mfma).
//  4) gemm_proj<3>: out = AO @ Wo^T -> f32 d_out.

typedef _Float16 f16;
typedef __attribute__((ext_vector_type(8))) _Float16 f16x8;
typedef __attribute__((ext_vector_type(4))) _Float16 f16x4;
typedef __attribute__((ext_vector_type(2))) _Float16 f16x2;
typedef __attribute__((ext_vector_type(4))) float f32x4;
typedef unsigned int u32;

// guaranteed v_pk_max_f16 lowering
static __device__ __forceinline__ f16x2 max2(f16x2 a, f16x2 b) {
    return __builtin_elementwise_max(a, b);
}

static __device__ __forceinline__ f16x2 shfl2(f16x2 v, int off) {
    union { f16x2 h; int i; } u;
    u.h = v;
    u.i = __shfl_xor(u.i, off);
    return u.h;
}

static __device__ __forceinline__ f16x2 pkrtz(float a, float b) {
    union { __fp16 __attribute__((ext_vector_type(2))) p; f16x2 h; } u;
    u.p = __builtin_amdgcn_cvt_pkrtz(a, b);
    return u.h;
}

// ---------------------------------------------------------------------------
// mask [2][2048][2048] int -> Mp[b][qt=128][w=8][c=16][8] u32
// ---------------------------------------------------------------------------
__global__ __launch_bounds__(256)
void pack_mask(const int* __restrict__ mask, u32* __restrict__ bits)
{
    int idx = blockIdx.x * 256 + threadIdx.x;        // (b*2048+q)*64 + wd
    const int4* p = (const int4*)&mask[(size_t)idx * 32];
    u32 v = 0;
#pragma unroll
    for (int i = 0; i < 8; i++) {
        int4 m = p[i];
        if (m.x != 0) v |= 1u << (i * 4 + 0);
        if (m.y != 0) v |= 1u << (i * 4 + 1);
        if (m.z != 0) v |= 1u << (i * 4 + 2);
        if (m.w != 0) v |= 1u << (i * 4 + 3);
    }
    const int wd = idx & 63;
    const int q = (idx >> 6) & 2047;
    const int b = idx >> 17;
    bits[(((size_t)(b * 128 + (q >> 4)) * 8 + (wd >> 3)) << 7) + ((q & 15) << 3) + (wd & 7)] = v;
}

// ---------------------------------------------------------------------------
// GEMM: C[M=4096, N=1024] = A[M,1024] * W[N,K=1024]^T
// MODE 0: Qp packed (*1/16)   1: Kp packed   2: Vp packed   3: OUT f32
// ---------------------------------------------------------------------------
template <int MODE>
__global__ __launch_bounds__(512)
void gemm_proj(const void* __restrict__ Ap, const float* __restrict__ Wp,
               void* __restrict__ Cp)
{
    __shared__ __align__(16) f16 As[128 * 40];
    __shared__ __align__(16) f16 Bs[128 * 40];

    const int tid = threadIdx.x;
    const int mBase = blockIdx.x * 128;
    const int nBase = blockIdx.y * 128;

    const int lane = tid & 63, w = tid >> 6;
    const int g = lane >> 4, c = lane & 15;
    const int wm = w >> 1, wn = w & 1;

    const int sr = tid >> 2;
    const int sq = tid & 3;

    f32x4 acc[2][4];
    const f32x4 vzero = {0.f, 0.f, 0.f, 0.f};
#pragma unroll
    for (int i = 0; i < 2; i++)
#pragma unroll
        for (int j = 0; j < 4; j++) acc[i][j] = vzero;

    for (int k0 = 0; k0 < 1024; k0 += 32) {
        __syncthreads();
        {
            f16x8 av;
            if constexpr (MODE == 3) {
                const f16* A = (const f16*)Ap;
                av = *(const f16x8*)&A[(size_t)(mBase + sr) * 1024 + k0 + sq * 8];
            } else {
                const float* A = (const float*)Ap;
                const float4* p = (const float4*)&A[(size_t)(mBase + sr) * 1024 + k0 + sq * 8];
                float4 x0 = p[0], x1 = p[1];
                av[0] = (f16)x0.x; av[1] = (f16)x0.y; av[2] = (f16)x0.z; av[3] = (f16)x0.w;
                av[4] = (f16)x1.x; av[5] = (f16)x1.y; av[6] = (f16)x1.z; av[7] = (f16)x1.w;
            }
            *(f16x8*)&As[sr * 40 + sq * 8] = av;

            const float4* pw = (const float4*)&Wp[(size_t)(nBase + sr) * 1024 + k0 + sq * 8];
            float4 w0 = pw[0], w1 = pw[1];
            f16x8 bv;
            bv[0] = (f16)w0.x; bv[1] = (f16)w0.y; bv[2] = (f16)w0.z; bv[3] = (f16)w0.w;
            bv[4] = (f16)w1.x; bv[5] = (f16)w1.y; bv[6] = (f16)w1.z; bv[7] = (f16)w1.w;
            *(f16x8*)&Bs[sr * 40 + sq * 8] = bv;
        }
        __syncthreads();

        f16x8 af[2], bf[4];
#pragma unroll
        for (int mt = 0; mt < 2; mt++)
            af[mt] = *(const f16x8*)&As[(wm * 32 + mt * 16 + c) * 40 + g * 8];
#pragma unroll
        for (int nt = 0; nt < 4; nt++)
            bf[nt] = *(const f16x8*)&Bs[(wn * 64 + nt * 16 + c) * 40 + g * 8];
#pragma unroll
        for (int mt = 0; mt < 2; mt++)
#pragma unroll
            for (int nt = 0; nt < 4; nt++)
                acc[mt][nt] = __builtin_amdgcn_mfma_f32_16x16x32_f16(af[mt], bf[nt], acc[mt][nt], 0, 0, 0);
    }

#pragma unroll
    for (int mt = 0; mt < 2; mt++)
#pragma unroll
        for (int nt = 0; nt < 4; nt++) {
            int row0 = mBase + wm * 32 + mt * 16 + g * 4;
            int col = nBase + wn * 64 + nt * 16 + c;
            if constexpr (MODE == 3) {
#pragma unroll
                for (int r = 0; r < 4; r++)
                    ((float*)Cp)[(size_t)(row0 + r) * 1024 + col] = acc[mt][nt][r];
            } else if constexpr (MODE == 2) {
                // Vp[bh][t][nd][c16][gv][4]: lane(c,g) holds V^T[d=nd*16+c][keys t*16+g*4..+4]
                int b = row0 >> 11, l0 = row0 & 2047;
                int h = col >> 6, dk = col & 63;
                int bh = b * 16 + h;
                int t = l0 >> 4, gv = (l0 & 15) >> 2;
                int nd = dk >> 4, c16 = dk & 15;
                f16x4 pv;
#pragma unroll
                for (int r = 0; r < 4; r++) pv[r] = (f16)acc[mt][nt][r];
                *(f16x4*)&((f16*)Cp)[(size_t)(bh * 128 + t) * 1024 + nd * 256 + c16 * 16 + gv * 4] = pv;
            } else {
                // Qp/Kp[bh][t][half][ck][gk][8]
#pragma unroll
                for (int r = 0; r < 4; r++) {
                    int row = row0 + r;
                    float v = acc[mt][nt][r];
                    if constexpr (MODE == 0) v *= 0.0625f;     // 1/sqrt(64) * 1/2
                    int b = row >> 11, l = row & 2047;
                    int h = col >> 6, dk = col & 63;
                    int bh = b * 16 + h;
                    int t = l >> 4, ck = l & 15;
                    int half = dk >> 5, gk = (dk >> 3) & 3, e = dk & 7;
                    ((f16*)Cp)[((size_t)(bh * 128 + t) * 2 + half) * 512 + ck * 32 + gk * 8 + e] = (f16)v;
                }
            }
        }
}

// ---------------------------------------------------------------------------
// Attention + exact 1.5-entmax (coalesced packed loads, packed-f16 VALU).
// ---------------------------------------------------------------------------
__global__ __launch_bounds__(512, 4)
void attn_entmax(const f16* __restrict__ Qp, const f16* __restrict__ Kp,
                 const f16* __restrict__ Vp, const u32* __restrict__ Mp,
                 f16* __restrict__ AO)
{
    constexpr int CAP = 512;
    constexpr int BSTR = 513;                        // padded row stride (f32)
    // Overlay: bucket f32[16][513] (32.8 KB) dies at taus barrier; Ored f32[8][16][68] after.
    __shared__ __align__(16) char LB[8 * 16 * 68 * 4];
    __shared__ int cntS[16];
    __shared__ float redM[8][16];
    __shared__ float redN[2][8][16][2];
    __shared__ float tau2s[16], zmaxs[16], taus[16];

    float* bucket = (float*)LB;
    float* Ored = (float*)LB;

    const int tid = threadIdx.x;
    const int w = tid >> 6, lane = tid & 63;
    const int g = lane >> 4, c = lane & 15;

    // XCD-aware swizzle: 4096 blocks = 8 XCD x (4 bh x 128 q-blocks)
    const int bid = blockIdx.x;
    const int q8 = bid >> 3;
    const int bh = (bid & 7) * 4 + (q8 >> 7);
    const int qt = q8 & 127;
    const int qb = qt * 16;
    const int b = bh >> 4, h = bh & 15;

    if (tid < 16) cntS[tid] = 0;

    // ---- Q B-fragments (coalesced: 1 KB per wave-instr) ----
    const f16* qbase = &Qp[(size_t)(bh * 128 + qt) * 1024 + c * 32 + g * 8];
    f16x8 bq0 = *(const f16x8*)qbase;
    f16x8 bq1 = *(const f16x8*)(qbase + 512);

    // ---- mask (coalesced: 512 B per wave-instr) ----
    const u32* mbase = &Mp[(((size_t)(b * 128 + qt) * 8 + w) << 7) + (c << 3)];
    uint4 mA = *(const uint4*)mbase;
    uint4 mB = *(const uint4*)(mbase + 4);
    u32 mb[8] = {mA.x, mA.y, mA.z, mA.w, mB.x, mB.y, mB.z, mB.w};

    // ---- scores S^T (swapped mfma(K,Q)) with fused pkrtz pack + max track ----
    f16x2 hS[32];
    f16x2 rmax; rmax.x = (f16)(-30000.f); rmax.y = (f16)(-30000.f);
    const f32x4 vz = {0.f, 0.f, 0.f, 0.f};
    const f16* kbaseP = &Kp[(size_t)(bh * 128 + w * 16) * 1024 + c * 32 + g * 8];
#pragma unroll
    for (int t = 0; t < 16; t++) {
        const f16* kp = kbaseP + (size_t)t * 1024;
        f16x8 ka0 = *(const f16x8*)kp;
        f16x8 ka1 = *(const f16x8*)(kp + 512);
        f32x4 z = __builtin_amdgcn_mfma_f32_16x16x32_f16(ka0, bq0, vz, 0, 0, 0);
        z = __builtin_amdgcn_mfma_f32_16x16x32_f16(ka1, bq1, z, 0, 0, 0);
        u32 b4 = mb[t >> 1] >> ((t & 1) * 16 + g * 4);
#pragma unroll
        for (int r = 0; r < 4; r++)
            if (!((b4 >> r) & 1)) z[r] = -30000.f;
        f16x2 p0 = pkrtz(z[0], z[1]);
        f16x2 p1 = pkrtz(z[2], z[3]);
        hS[2 * t] = p0;
        hS[2 * t + 1] = p1;
        rmax = max2(rmax, max2(p0, p1));
    }

    // ---- zmax per query ----
    float zx = fmaxf((float)rmax.x, (float)rmax.y);
    zx = fmaxf(zx, __shfl_xor(zx, 16));
    zx = fmaxf(zx, __shfl_xor(zx, 32));
    if (lane < 16) redM[w][c] = zx;
    __syncthreads();
    float zmax = -3e38f;
#pragma unroll
    for (int ww = 0; ww < 8; ww++) zmax = fmaxf(zmax, redM[ww][c]);

    // ---- TWO cross-wave Newton iters from below (PACKED f16 scans) ----
    f16x2 zero2; zero2.x = (f16)0.f; zero2.y = (f16)0.f;
    float tau = zmax - 1.0f;
    int buf = 0;
#pragma unroll 1
    for (int it = 0; it < 2; ++it) {
        f16 tn = (f16)tau;
        f16x2 tv; tv.x = tn; tv.y = tn;
        f16x2 s1p = zero2, s2p = zero2;
#pragma unroll
        for (int i = 0; i < 32; i++) {
            f16x2 d = max2(hS[i] - tv, zero2);
            s1p = s1p + d;
            s2p = s2p + d * d;
        }
        s1p = s1p + shfl2(s1p, 16);
        s2p = s2p + shfl2(s2p, 16);
        s1p = s1p + shfl2(s1p, 32);
        s2p = s2p + shfl2(s2p, 32);
        float s1 = (float)s1p.x + (float)s1p.y;
        float s2 = (float)s2p.x + (float)s2p.y;
        if (lane < 16) { redN[buf][w][c][0] = s1; redN[buf][w][c][1] = s2; }
        __syncthreads();
        float a = 0.f, f = 0.f;
#pragma unroll
        for (int ww = 0; ww < 8; ww++) {
            float2 v2 = *(const float2*)&redN[buf][ww][c][0];
            a += v2.x; f += v2.y;
        }
        if (a > 1e-9f)
            tau = fminf(tau + (f - 1.0f) / (2.0f * a), zmax - 1e-3f);
        buf ^= 1;
    }
    if (w == 0 && lane < 16) { tau2s[c] = tau; zmaxs[c] = zmax; }

    // ---- filter survivors (f16 compares, 0.02 margin for packed-f16 noise) ----
    const f16 thrh = (f16)(tau - 0.02f);
#pragma unroll
    for (int i = 0; i < 32; i++) {
        if (hS[i].x > thrh) { int id = atomicAdd(&cntS[c], 1); if (id < CAP) bucket[c * BSTR + id] = (float)hS[i].x; }
        if (hS[i].y > thrh) { int id = atomicAdd(&cntS[c], 1); if (id < CAP) bucket[c * BSTR + id] = (float)hS[i].y; }
    }
    __syncthreads();

    // ---- bucket solve: quarter-wave per query (4 queries / wave), f32 ----
    {
        const int qi = 4 * w + (lane >> 4);
        const int sl = lane & 15;
        const int cnt = min(cntS[qi], CAP);
        const int ns = (cnt + 15) >> 4;
        float tq = tau2s[qi];
        const float zq = zmaxs[qi];
#pragma unroll 1
        for (int it = 0; it < 4; ++it) {
            float s1 = 0.f, s2 = 0.f;
#pragma unroll 1
            for (int s = 0; s < ns; s++) {
                int i = sl + 16 * s;
                float v = (i < cnt) ? bucket[qi * BSTR + i] : -1e30f;
                float d = fmaxf(v - tq, 0.f);
                s1 += d; s2 = fmaf(d, d, s2);
            }
#pragma unroll
            for (int off = 1; off <= 8; off <<= 1) {
                s1 += __shfl_xor(s1, off);
                s2 += __shfl_xor(s2, off);
            }
            if (s1 > 1e-12f) tq = fminf(tq + (s2 - 1.0f) / (2.0f * s1), zq - 1e-3f);
        }
#pragma unroll 1
        for (int rf = 0; rf < 3; ++rf) {
            float kc = 0.f, s1 = 0.f, s2 = 0.f;
#pragma unroll 1
            for (int s = 0; s < ns; s++) {
                int i = sl + 16 * s;
                float v = (i < cnt) ? bucket[qi * BSTR + i] : -1e30f;
                float d = v - tq;
                if (d > 0.f) { kc += 1.f; s1 += d; s2 = fmaf(d, d, s2); }
            }
#pragma unroll
            for (int off = 1; off <= 8; off <<= 1) {
                kc += __shfl_xor(kc, off);
                s1 += __shfl_xor(s1, off);
                s2 += __shfl_xor(s2, off);
            }
            float K_ = fmaxf(kc, 1.0f);
            float disc = fmaxf(s1 * s1 - K_ * (s2 - 1.0f), 0.f);
            tq += (s1 - sqrtf(disc)) / K_;
        }
        if (sl == 0) taus[qi] = tq;
    }
    __syncthreads();     // taus ready; bucket dead -> LB becomes Ored

    // ---- P = ((z-tau)_+)^2 PACKED -> PV from regs (coalesced Vp loads) ----
    const f16 tch = (f16)taus[c];
    f16x2 tv2; tv2.x = tch; tv2.y = tch;
    f32x4 O[4];
#pragma unroll
    for (int nd = 0; nd < 4; nd++) O[nd] = vz;
    const f16* vbase = &Vp[(size_t)(bh * 128 + w * 16) * 1024 + c * 16 + g * 4];
#pragma unroll
    for (int t = 0; t < 16; t++) {
        f16x2 da = max2(hS[2 * t] - tv2, zero2);
        f16x2 db = max2(hS[2 * t + 1] - tv2, zero2);
        da = da * da;
        db = db * db;
        union { f16x4 v4; f16x2 h2[2]; } pu;
        pu.h2[0] = da; pu.h2[1] = db;
        const f16* vp = vbase + (size_t)t * 1024;
#pragma unroll
        for (int nd = 0; nd < 4; nd++) {
            f16x4 va = *(const f16x4*)(vp + nd * 256);
            O[nd] = __builtin_amdgcn_mfma_f32_16x16x16f16(va, pu.v4, O[nd], 0, 0, 0);
        }
    }

    // ---- cross-wave O reduction (Ored overlays bucket) ----
#pragma unroll
    for (int nd = 0; nd < 4; nd++)
        *(f32x4*)&Ored[(w * 16 + c) * 68 + nd * 16 + g * 4] = O[nd];
    __syncthreads();

    const int qrow = tid >> 5;
    const int dp = tid & 31;
    float o0 = 0.f, o1 = 0.f;
#pragma unroll
    for (int ww = 0; ww < 8; ww++) {
        float2 v = *(const float2*)&Ored[(ww * 16 + qrow) * 68 + dp * 2];
        o0 += v.x; o1 += v.y;
    }
    f16x2 pk = pkrtz(o0, o1);
    *(f16x2*)&AO[(size_t)(b * 2048 + qb + qrow) * 1024 + h * 64 + dp * 2] = pk;
}

// ---------------------------------------------------------------------------
extern "C" void kernel_launch(void* const* d_in, const int* in_sizes, int n_in,
                              void* d_out, int out_size, void* d_ws, size_t ws_size,
                              hipStream_t stream)
{
    const float* q  = (const float*)d_in[0];
    const float* k  = (const float*)d_in[1];
    const float* v  = (const float*)d_in[2];
    const int* mask = (const int*)d_in[3];
    const float* wq = (const float*)d_in[4];
    const float* wk = (const float*)d_in[5];
    const float* wv = (const float*)d_in[6];
    const float* wo = (const float*)d_in[7];

    char* ws = (char*)d_ws;
    const size_t SZ = 8388608ull;            // 8 MB per f16 buffer
    f16* Qb  = (f16*)(ws);
    f16* Kb  = (f16*)(ws + SZ);
    f16* Vb  = (f16*)(ws + 2 * SZ);
    f16* AOb = (f16*)(ws + 3 * SZ);
    u32* Mb  = (u32*)(ws + 4 * SZ);          // 1 MB packed mask

    pack_mask<<<1024, 256, 0, stream>>>(mask, Mb);

    dim3 gg(32, 8);
    gemm_proj<0><<<gg, 512, 0, stream>>>(q, wq, Qb);
    gemm_proj<1><<<gg, 512, 0, stream>>>(k, wk, Kb);
    gemm_proj<2><<<gg, 512, 0, stream>>>(v, wv, Vb);
    attn_entmax<<<4096, 512, 0, stream>>>(Qb, Kb, Vb, Mb, AOb);
    gemm_proj<3><<<gg, 512, 0, stream>>>(AOb, wo, d_out);
}

// Round 14
// 420.951 us; speedup vs baseline: 1.0184x; 1.0184x over previous
//
#include <hip/hip_runtime.h>

// Shapes: B=2, L=2048, D_MODEL=1024, H=16, D_K=64
// Pipeline (R14 = R13 + deep explicit prefetch in attn, <=128 VGPR):
//  0) pack_mask: mask int32 [B][L][L] -> Mp[b][qt][w][c][8] u32 (wave-contiguous).
//  1) gemm_proj<0/1>: Q/K proj; epilogue writes FRAGMENT-PACKED
//     Qp/Kp[bh][tile][half][c][g][8 f16]  (1 KB contiguous per wave-load).
//  2) gemm_proj<2>: V proj; epilogue writes Vp[bh][tile][nd][c][g][4 f16].
//  3) attn_entmax: 16 q x 2048 k, 8 waves, XCD-swizzled grid, coalesced loads.
//     QK^T in 4-tile chunks with double-buffered K (4 loads in flight);
//     TWO cross-wave Newton iters (packed f16), filter at tau2-0.02 into f32
//     buckets (CAP=512, stride 513); V chunk 0 prefetched BEFORE the bucket
//     solve; PV in 2-tile double-buffered chunks. P packed f16.
//  4) gemm_proj<3>: out = AO @ Wo^T -> f32 d_out.

typedef _Float16 f16;
typedef __attribute__((ext_vector_type(8))) _Float16 f16x8;
typedef __attribute__((ext_vector_type(4))) _Float16 f16x4;
typedef __attribute__((ext_vector_type(2))) _Float16 f16x2;
typedef __attribute__((ext_vector_type(4))) float f32x4;
typedef unsigned int u32;

// guaranteed v_pk_max_f16 lowering
static __device__ __forceinline__ f16x2 max2(f16x2 a, f16x2 b) {
    return __builtin_elementwise_max(a, b);
}

static __device__ __forceinline__ f16x2 shfl2(f16x2 v, int off) {
    union { f16x2 h; int i; } u;
    u.h = v;
    u.i = __shfl_xor(u.i, off);
    return u.h;
}

static __device__ __forceinline__ f16x2 pkrtz(float a, float b) {
    union { __fp16 __attribute__((ext_vector_type(2))) p; f16x2 h; } u;
    u.p = __builtin_amdgcn_cvt_pkrtz(a, b);
    return u.h;
}

// ---------------------------------------------------------------------------
// mask [2][2048][2048] int -> Mp[b][qt=128][w=8][c=16][8] u32
// ---------------------------------------------------------------------------
__global__ __launch_bounds__(256)
void pack_mask(const int* __restrict__ mask, u32* __restrict__ bits)
{
    int idx = blockIdx.x * 256 + threadIdx.x;        // (b*2048+q)*64 + wd
    const int4* p = (const int4*)&mask[(size_t)idx * 32];
    u32 v = 0;
#pragma unroll
    for (int i = 0; i < 8; i++) {
        int4 m = p[i];
        if (m.x != 0) v |= 1u << (i * 4 + 0);
        if (m.y != 0) v |= 1u << (i * 4 + 1);
        if (m.z != 0) v |= 1u << (i * 4 + 2);
        if (m.w != 0) v |= 1u << (i * 4 + 3);
    }
    const int wd = idx & 63;
    const int q = (idx >> 6) & 2047;
    const int b = idx >> 17;
    bits[(((size_t)(b * 128 + (q >> 4)) * 8 + (wd >> 3)) << 7) + ((q & 15) << 3) + (wd & 7)] = v;
}

// ---------------------------------------------------------------------------
// GEMM: C[M=4096, N=1024] = A[M,1024] * W[N,K=1024]^T
// MODE 0: Qp packed (*1/16)   1: Kp packed   2: Vp packed   3: OUT f32
// ---------------------------------------------------------------------------
template <int MODE>
__global__ __launch_bounds__(512)
void gemm_proj(const void* __restrict__ Ap, const float* __restrict__ Wp,
               void* __restrict__ Cp)
{
    __shared__ __align__(16) f16 As[128 * 40];
    __shared__ __align__(16) f16 Bs[128 * 40];

    const int tid = threadIdx.x;
    const int mBase = blockIdx.x * 128;
    const int nBase = blockIdx.y * 128;

    const int lane = tid & 63, w = tid >> 6;
    const int g = lane >> 4, c = lane & 15;
    const int wm = w >> 1, wn = w & 1;

    const int sr = tid >> 2;
    const int sq = tid & 3;

    f32x4 acc[2][4];
    const f32x4 vzero = {0.f, 0.f, 0.f, 0.f};
#pragma unroll
    for (int i = 0; i < 2; i++)
#pragma unroll
        for (int j = 0; j < 4; j++) acc[i][j] = vzero;

    for (int k0 = 0; k0 < 1024; k0 += 32) {
        __syncthreads();
        {
            f16x8 av;
            if constexpr (MODE == 3) {
                const f16* A = (const f16*)Ap;
                av = *(const f16x8*)&A[(size_t)(mBase + sr) * 1024 + k0 + sq * 8];
            } else {
                const float* A = (const float*)Ap;
                const float4* p = (const float4*)&A[(size_t)(mBase + sr) * 1024 + k0 + sq * 8];
                float4 x0 = p[0], x1 = p[1];
                av[0] = (f16)x0.x; av[1] = (f16)x0.y; av[2] = (f16)x0.z; av[3] = (f16)x0.w;
                av[4] = (f16)x1.x; av[5] = (f16)x1.y; av[6] = (f16)x1.z; av[7] = (f16)x1.w;
            }
            *(f16x8*)&As[sr * 40 + sq * 8] = av;

            const float4* pw = (const float4*)&Wp[(size_t)(nBase + sr) * 1024 + k0 + sq * 8];
            float4 w0 = pw[0], w1 = pw[1];
            f16x8 bv;
            bv[0] = (f16)w0.x; bv[1] = (f16)w0.y; bv[2] = (f16)w0.z; bv[3] = (f16)w0.w;
            bv[4] = (f16)w1.x; bv[5] = (f16)w1.y; bv[6] = (f16)w1.z; bv[7] = (f16)w1.w;
            *(f16x8*)&Bs[sr * 40 + sq * 8] = bv;
        }
        __syncthreads();

        f16x8 af[2], bf[4];
#pragma unroll
        for (int mt = 0; mt < 2; mt++)
            af[mt] = *(const f16x8*)&As[(wm * 32 + mt * 16 + c) * 40 + g * 8];
#pragma unroll
        for (int nt = 0; nt < 4; nt++)
            bf[nt] = *(const f16x8*)&Bs[(wn * 64 + nt * 16 + c) * 40 + g * 8];
#pragma unroll
        for (int mt = 0; mt < 2; mt++)
#pragma unroll
            for (int nt = 0; nt < 4; nt++)
                acc[mt][nt] = __builtin_amdgcn_mfma_f32_16x16x32_f16(af[mt], bf[nt], acc[mt][nt], 0, 0, 0);
    }

#pragma unroll
    for (int mt = 0; mt < 2; mt++)
#pragma unroll
        for (int nt = 0; nt < 4; nt++) {
            int row0 = mBase + wm * 32 + mt * 16 + g * 4;
            int col = nBase + wn * 64 + nt * 16 + c;
            if constexpr (MODE == 3) {
#pragma unroll
                for (int r = 0; r < 4; r++)
                    ((float*)Cp)[(size_t)(row0 + r) * 1024 + col] = acc[mt][nt][r];
            } else if constexpr (MODE == 2) {
                // Vp[bh][t][nd][c16][gv][4]: lane(c,g) holds V^T[d=nd*16+c][keys t*16+g*4..+4]
                int b = row0 >> 11, l0 = row0 & 2047;
                int h = col >> 6, dk = col & 63;
                int bh = b * 16 + h;
                int t = l0 >> 4, gv = (l0 & 15) >> 2;
                int nd = dk >> 4, c16 = dk & 15;
                f16x4 pv;
#pragma unroll
                for (int r = 0; r < 4; r++) pv[r] = (f16)acc[mt][nt][r];
                *(f16x4*)&((f16*)Cp)[(size_t)(bh * 128 + t) * 1024 + nd * 256 + c16 * 16 + gv * 4] = pv;
            } else {
                // Qp/Kp[bh][t][half][ck][gk][8]
#pragma unroll
                for (int r = 0; r < 4; r++) {
                    int row = row0 + r;
                    float v = acc[mt][nt][r];
                    if constexpr (MODE == 0) v *= 0.0625f;     // 1/sqrt(64) * 1/2
                    int b = row >> 11, l = row & 2047;
                    int h = col >> 6, dk = col & 63;
                    int bh = b * 16 + h;
                    int t = l >> 4, ck = l & 15;
                    int half = dk >> 5, gk = (dk >> 3) & 3, e = dk & 7;
                    ((f16*)Cp)[((size_t)(bh * 128 + t) * 2 + half) * 512 + ck * 32 + gk * 8 + e] = (f16)v;
                }
            }
        }
}

// ---------------------------------------------------------------------------
// Attention + exact 1.5-entmax (coalesced loads + deep explicit prefetch).
// ---------------------------------------------------------------------------
__global__ __launch_bounds__(512, 4)
void attn_entmax(const f16* __restrict__ Qp, const f16* __restrict__ Kp,
                 const f16* __restrict__ Vp, const u32* __restrict__ Mp,
                 f16* __restrict__ AO)
{
    constexpr int CAP = 512;
    constexpr int BSTR = 513;                        // padded row stride (f32)
    // Overlay: bucket f32[16][513] (32.8 KB) dies at taus barrier; Ored f32[8][16][68] after.
    __shared__ __align__(16) char LB[8 * 16 * 68 * 4];
    __shared__ int cntS[16];
    __shared__ float redM[8][16];
    __shared__ float redN[2][8][16][2];
    __shared__ float tau2s[16], zmaxs[16], taus[16];

    float* bucket = (float*)LB;
    float* Ored = (float*)LB;

    const int tid = threadIdx.x;
    const int w = tid >> 6, lane = tid & 63;
    const int g = lane >> 4, c = lane & 15;

    // XCD-aware swizzle: 4096 blocks = 8 XCD x (4 bh x 128 q-blocks)
    const int bid = blockIdx.x;
    const int q8 = bid >> 3;
    const int bh = (bid & 7) * 4 + (q8 >> 7);
    const int qt = q8 & 127;
    const int qb = qt * 16;
    const int b = bh >> 4, h = bh & 15;

    if (tid < 16) cntS[tid] = 0;

    // ---- Q B-fragments (coalesced: 1 KB per wave-instr) ----
    const f16* qbase = &Qp[(size_t)(bh * 128 + qt) * 1024 + c * 32 + g * 8];
    f16x8 bq0 = *(const f16x8*)qbase;
    f16x8 bq1 = *(const f16x8*)(qbase + 512);

    // ---- mask (coalesced: 512 B per wave-instr) ----
    const u32* mbase = &Mp[(((size_t)(b * 128 + qt) * 8 + w) << 7) + (c << 3)];
    uint4 mA = *(const uint4*)mbase;
    uint4 mB = *(const uint4*)(mbase + 4);
    u32 mb[8] = {mA.x, mA.y, mA.z, mA.w, mB.x, mB.y, mB.z, mB.w};

    // ---- scores: 4-tile chunks, double-buffered K (4 loads in flight) ----
    f16x2 hS[32];
    f16x2 rmax; rmax.x = (f16)(-30000.f); rmax.y = (f16)(-30000.f);
    const f32x4 vz = {0.f, 0.f, 0.f, 0.f};
    const f16* kbaseP = &Kp[(size_t)(bh * 128 + w * 16) * 1024 + c * 32 + g * 8];

    f16x8 kb[2][8];                                  // [buf][tile*2+half], 32 VGPR/buf
#pragma unroll
    for (int i = 0; i < 4; i++) {
        const f16* kp = kbaseP + (size_t)i * 1024;
        kb[0][2 * i]     = *(const f16x8*)kp;
        kb[0][2 * i + 1] = *(const f16x8*)(kp + 512);
    }
#pragma unroll
    for (int ch = 0; ch < 4; ch++) {
        if (ch < 3) {
#pragma unroll
            for (int i = 0; i < 4; i++) {
                const f16* kp = kbaseP + (size_t)((ch + 1) * 4 + i) * 1024;
                kb[(ch + 1) & 1][2 * i]     = *(const f16x8*)kp;
                kb[(ch + 1) & 1][2 * i + 1] = *(const f16x8*)(kp + 512);
            }
        }
#pragma unroll
        for (int i = 0; i < 4; i++) {
            const int t = ch * 4 + i;
            f32x4 z = __builtin_amdgcn_mfma_f32_16x16x32_f16(kb[ch & 1][2 * i], bq0, vz, 0, 0, 0);
            z = __builtin_amdgcn_mfma_f32_16x16x32_f16(kb[ch & 1][2 * i + 1], bq1, z, 0, 0, 0);
            u32 b4 = mb[t >> 1] >> ((t & 1) * 16 + g * 4);
#pragma unroll
            for (int r = 0; r < 4; r++)
                if (!((b4 >> r) & 1)) z[r] = -30000.f;
            f16x2 p0 = pkrtz(z[0], z[1]);
            f16x2 p1 = pkrtz(z[2], z[3]);
            hS[2 * t] = p0;
            hS[2 * t + 1] = p1;
            rmax = max2(rmax, max2(p0, p1));
        }
    }

    // ---- zmax per query ----
    float zx = fmaxf((float)rmax.x, (float)rmax.y);
    zx = fmaxf(zx, __shfl_xor(zx, 16));
    zx = fmaxf(zx, __shfl_xor(zx, 32));
    if (lane < 16) redM[w][c] = zx;
    __syncthreads();
    float zmax = -3e38f;
#pragma unroll
    for (int ww = 0; ww < 8; ww++) zmax = fmaxf(zmax, redM[ww][c]);

    // ---- TWO cross-wave Newton iters from below (PACKED f16 scans) ----
    f16x2 zero2; zero2.x = (f16)0.f; zero2.y = (f16)0.f;
    float tau = zmax - 1.0f;
    int buf = 0;
#pragma unroll 1
    for (int it = 0; it < 2; ++it) {
        f16 tn = (f16)tau;
        f16x2 tv; tv.x = tn; tv.y = tn;
        f16x2 s1p = zero2, s2p = zero2;
#pragma unroll
        for (int i = 0; i < 32; i++) {
            f16x2 d = max2(hS[i] - tv, zero2);
            s1p = s1p + d;
            s2p = s2p + d * d;
        }
        s1p = s1p + shfl2(s1p, 16);
        s2p = s2p + shfl2(s2p, 16);
        s1p = s1p + shfl2(s1p, 32);
        s2p = s2p + shfl2(s2p, 32);
        float s1 = (float)s1p.x + (float)s1p.y;
        float s2 = (float)s2p.x + (float)s2p.y;
        if (lane < 16) { redN[buf][w][c][0] = s1; redN[buf][w][c][1] = s2; }
        __syncthreads();
        float a = 0.f, f = 0.f;
#pragma unroll
        for (int ww = 0; ww < 8; ww++) {
            float2 v2 = *(const float2*)&redN[buf][ww][c][0];
            a += v2.x; f += v2.y;
        }
        if (a > 1e-9f)
            tau = fminf(tau + (f - 1.0f) / (2.0f * a), zmax - 1e-3f);
        buf ^= 1;
    }
    if (w == 0 && lane < 16) { tau2s[c] = tau; zmaxs[c] = zmax; }

    // ---- filter survivors (f16 compares, 0.02 margin) ----
    const f16 thrh = (f16)(tau - 0.02f);
#pragma unroll
    for (int i = 0; i < 32; i++) {
        if (hS[i].x > thrh) { int id = atomicAdd(&cntS[c], 1); if (id < CAP) bucket[c * BSTR + id] = (float)hS[i].x; }
        if (hS[i].y > thrh) { int id = atomicAdd(&cntS[c], 1); if (id < CAP) bucket[c * BSTR + id] = (float)hS[i].y; }
    }
    __syncthreads();

    // ---- issue V chunk 0 (2 tiles) now: latency hides under bucket solve ----
    const f16* vbase = &Vp[(size_t)(bh * 128 + w * 16) * 1024 + c * 16 + g * 4];
    f16x4 vb[2][8];                                  // [buf][tile*4+nd], 16 VGPR/buf
#pragma unroll
    for (int i = 0; i < 2; i++)
#pragma unroll
        for (int nd = 0; nd < 4; nd++)
            vb[0][i * 4 + nd] = *(const f16x4*)(vbase + (size_t)i * 1024 + nd * 256);

    // ---- bucket solve: quarter-wave per query (4 queries / wave), f32 ----
    {
        const int qi = 4 * w + (lane >> 4);
        const int sl = lane & 15;
        const int cnt = min(cntS[qi], CAP);
        const int ns = (cnt + 15) >> 4;
        float tq = tau2s[qi];
        const float zq = zmaxs[qi];
#pragma unroll 1
        for (int it = 0; it < 4; ++it) {
            float s1 = 0.f, s2 = 0.f;
#pragma unroll 1
            for (int s = 0; s < ns; s++) {
                int i = sl + 16 * s;
                float v = (i < cnt) ? bucket[qi * BSTR + i] : -1e30f;
                float d = fmaxf(v - tq, 0.f);
                s1 += d; s2 = fmaf(d, d, s2);
            }
#pragma unroll
            for (int off = 1; off <= 8; off <<= 1) {
                s1 += __shfl_xor(s1, off);
                s2 += __shfl_xor(s2, off);
            }
            if (s1 > 1e-12f) tq = fminf(tq + (s2 - 1.0f) / (2.0f * s1), zq - 1e-3f);
        }
#pragma unroll 1
        for (int rf = 0; rf < 3; ++rf) {
            float kc = 0.f, s1 = 0.f, s2 = 0.f;
#pragma unroll 1
            for (int s = 0; s < ns; s++) {
                int i = sl + 16 * s;
                float v = (i < cnt) ? bucket[qi * BSTR + i] : -1e30f;
                float d = v - tq;
                if (d > 0.f) { kc += 1.f; s1 += d; s2 = fmaf(d, d, s2); }
            }
#pragma unroll
            for (int off = 1; off <= 8; off <<= 1) {
                kc += __shfl_xor(kc, off);
                s1 += __shfl_xor(s1, off);
                s2 += __shfl_xor(s2, off);
            }
            float K_ = fmaxf(kc, 1.0f);
            float disc = fmaxf(s1 * s1 - K_ * (s2 - 1.0f), 0.f);
            tq += (s1 - sqrtf(disc)) / K_;
        }
        if (sl == 0) taus[qi] = tq;
    }
    __syncthreads();     // taus ready; bucket dead -> LB becomes Ored

    // ---- P packed + PV: 2-tile chunks, double-buffered V ----
    const f16 tch = (f16)taus[c];
    f16x2 tv2; tv2.x = tch; tv2.y = tch;
    f32x4 O[4];
#pragma unroll
    for (int nd = 0; nd < 4; nd++) O[nd] = vz;
#pragma unroll
    for (int ch = 0; ch < 8; ch++) {
        if (ch < 7) {
#pragma unroll
            for (int i = 0; i < 2; i++)
#pragma unroll
                for (int nd = 0; nd < 4; nd++)
                    vb[(ch + 1) & 1][i * 4 + nd] =
                        *(const f16x4*)(vbase + (size_t)((ch + 1) * 2 + i) * 1024 + nd * 256);
        }
#pragma unroll
        for (int i = 0; i < 2; i++) {
            const int t = ch * 2 + i;
            f16x2 da = max2(hS[2 * t] - tv2, zero2);
            f16x2 db = max2(hS[2 * t + 1] - tv2, zero2);
            da = da * da;
            db = db * db;
            union { f16x4 v4; f16x2 h2[2]; } pu;
            pu.h2[0] = da; pu.h2[1] = db;
#pragma unroll
            for (int nd = 0; nd < 4; nd++)
                O[nd] = __builtin_amdgcn_mfma_f32_16x16x16f16(vb[ch & 1][i * 4 + nd], pu.v4, O[nd], 0, 0, 0);
        }
    }

    // ---- cross-wave O reduction (Ored overlays bucket) ----
#pragma unroll
    for (int nd = 0; nd < 4; nd++)
        *(f32x4*)&Ored[(w * 16 + c) * 68 + nd * 16 + g * 4] = O[nd];
    __syncthreads();

    const int qrow = tid >> 5;
    const int dp = tid & 31;
    float o0 = 0.f, o1 = 0.f;
#pragma unroll
    for (int ww = 0; ww < 8; ww++) {
        float2 v = *(const float2*)&Ored[(ww * 16 + qrow) * 68 + dp * 2];
        o0 += v.x; o1 += v.y;
    }
    f16x2 pk = pkrtz(o0, o1);
    *(f16x2*)&AO[(size_t)(b * 2048 + qb + qrow) * 1024 + h * 64 + dp * 2] = pk;
}

// ---------------------------------------------------------------------------
extern "C" void kernel_launch(void* const* d_in, const int* in_sizes, int n_in,
                              void* d_out, int out_size, void* d_ws, size_t ws_size,
                              hipStream_t stream)
{
    const float* q  = (const float*)d_in[0];
    const float* k  = (const float*)d_in[1];
    const float* v  = (const float*)d_in[2];
    const int* mask = (const int*)d_in[3];
    const float* wq = (const float*)d_in[4];
    const float* wk = (const float*)d_in[5];
    const float* wv = (const float*)d_in[6];
    const float* wo = (const float*)d_in[7];

    char* ws = (char*)d_ws;
    const size_t SZ = 8388608ull;            // 8 MB per f16 buffer
    f16* Qb  = (f16*)(ws);
    f16* Kb  = (f16*)(ws + SZ);
    f16* Vb  = (f16*)(ws + 2 * SZ);
    f16* AOb = (f16*)(ws + 3 * SZ);
    u32* Mb  = (u32*)(ws + 4 * SZ);          // 1 MB packed mask

    pack_mask<<<1024, 256, 0, stream>>>(mask, Mb);

    dim3 gg(32, 8);
    gemm_proj<0><<<gg, 512, 0, stream>>>(q, wq, Qb);
    gemm_proj<1><<<gg, 512, 0, stream>>>(k, wk, Kb);
    gemm_proj<2><<<gg, 512, 0, stream>>>(v, wv, Vb);
    attn_entmax<<<4096, 512, 0, stream>>>(Qb, Kb, Vb, Mb, AOb);
    gemm_proj<3><<<gg, 512, 0, stream>>>(AOb, wo, d_out);
}

// Round 15
// 376.283 us; speedup vs baseline: 1.1393x; 1.1187x over previous
//
#include <hip/hip_runtime.h>

// Shapes: B=2, L=2048, D_MODEL=1024, H=16, D_K=64
// Pipeline (R15 = R14 + mask fast-path + sign-bit filter + fused QKV GEMM):
//  0) pack_mask: mask int32 [B][L][L] -> Mp[b][qt][w][c][8] u32 (wave-contiguous).
//  1) gemm_qkv: Q/K/V projections in ONE kernel (wsel = by>>3 selects A,W);
//     epilogues write FRAGMENT-PACKED Qp/Kp[bh][t][half][c][g][8] and
//     Vp[bh][t][nd][c16][gv][4].
//  2) attn_entmax: 16 q x 2048 k, 8 waves, XCD-swizzled grid, coalesced loads.
//     Swapped QK^T (4-tile chunks) -> f16x2 scores; mask applied only when the
//     32-key mask word != all-ones (fast-path for dense masks). TWO cross-wave
//     Newton iters (packed f16), filter via packed sign-bit test at tau2-0.02
//     into f32 buckets (CAP=512, stride 513), quarter-wave f32 solve (4 Newton
//     + 3 exact support refines), P packed f16 -> PV from regs (16x16x16).
//  3) gemm_out: out = AO @ Wo^T -> f32 d_out.

typedef _Float16 f16;
typedef __attribute__((ext_vector_type(8))) _Float16 f16x8;
typedef __attribute__((ext_vector_type(4))) _Float16 f16x4;
typedef __attribute__((ext_vector_type(2))) _Float16 f16x2;
typedef __attribute__((ext_vector_type(4))) float f32x4;
typedef unsigned int u32;

// guaranteed v_pk_max_f16 lowering
static __device__ __forceinline__ f16x2 max2(f16x2 a, f16x2 b) {
    return __builtin_elementwise_max(a, b);
}

static __device__ __forceinline__ f16x2 shfl2(f16x2 v, int off) {
    union { f16x2 h; int i; } u;
    u.h = v;
    u.i = __shfl_xor(u.i, off);
    return u.h;
}

static __device__ __forceinline__ f16x2 pkrtz(float a, float b) {
    union { __fp16 __attribute__((ext_vector_type(2))) p; f16x2 h; } u;
    u.p = __builtin_amdgcn_cvt_pkrtz(a, b);
    return u.h;
}

// ---------------------------------------------------------------------------
// mask [2][2048][2048] int -> Mp[b][qt=128][w=8][c=16][8] u32
// ---------------------------------------------------------------------------
__global__ __launch_bounds__(256)
void pack_mask(const int* __restrict__ mask, u32* __restrict__ bits)
{
    int idx = blockIdx.x * 256 + threadIdx.x;        // (b*2048+q)*64 + wd
    const int4* p = (const int4*)&mask[(size_t)idx * 32];
    u32 v = 0;
#pragma unroll
    for (int i = 0; i < 8; i++) {
        int4 m = p[i];
        if (m.x != 0) v |= 1u << (i * 4 + 0);
        if (m.y != 0) v |= 1u << (i * 4 + 1);
        if (m.z != 0) v |= 1u << (i * 4 + 2);
        if (m.w != 0) v |= 1u << (i * 4 + 3);
    }
    const int wd = idx & 63;
    const int q = (idx >> 6) & 2047;
    const int b = idx >> 17;
    bits[(((size_t)(b * 128 + (q >> 4)) * 8 + (wd >> 3)) << 7) + ((q & 15) << 3) + (wd & 7)] = v;
}

// ---------------------------------------------------------------------------
// Fused Q/K/V projection: C = A @ W^T, wsel = by>>3 picks (A, W, epilogue).
// wsel 0: Q (scale 1/16, Qp-pack)  1: K (Kp-pack)  2: V (Vp-pack)
// ---------------------------------------------------------------------------
__global__ __launch_bounds__(512)
void gemm_qkv(const float* __restrict__ Aq, const float* __restrict__ Ak,
              const float* __restrict__ Av, const float* __restrict__ W0,
              const float* __restrict__ W1, const float* __restrict__ W2,
              f16* __restrict__ Qp, f16* __restrict__ Kp, f16* __restrict__ Vp)
{
    __shared__ __align__(16) f16 As[128 * 40];
    __shared__ __align__(16) f16 Bs[128 * 40];

    const int tid = threadIdx.x;
    const int wsel = blockIdx.y >> 3;
    const float* A  = wsel == 0 ? Aq : (wsel == 1 ? Ak : Av);
    const float* Wp = wsel == 0 ? W0 : (wsel == 1 ? W1 : W2);
    const int mBase = blockIdx.x * 128;
    const int nBase = (blockIdx.y & 7) * 128;

    const int lane = tid & 63, w = tid >> 6;
    const int g = lane >> 4, c = lane & 15;
    const int wm = w >> 1, wn = w & 1;

    const int sr = tid >> 2;
    const int sq = tid & 3;

    f32x4 acc[2][4];
    const f32x4 vzero = {0.f, 0.f, 0.f, 0.f};
#pragma unroll
    for (int i = 0; i < 2; i++)
#pragma unroll
        for (int j = 0; j < 4; j++) acc[i][j] = vzero;

    for (int k0 = 0; k0 < 1024; k0 += 32) {
        __syncthreads();
        {
            const float4* p = (const float4*)&A[(size_t)(mBase + sr) * 1024 + k0 + sq * 8];
            float4 x0 = p[0], x1 = p[1];
            f16x8 av;
            av[0] = (f16)x0.x; av[1] = (f16)x0.y; av[2] = (f16)x0.z; av[3] = (f16)x0.w;
            av[4] = (f16)x1.x; av[5] = (f16)x1.y; av[6] = (f16)x1.z; av[7] = (f16)x1.w;
            *(f16x8*)&As[sr * 40 + sq * 8] = av;

            const float4* pw = (const float4*)&Wp[(size_t)(nBase + sr) * 1024 + k0 + sq * 8];
            float4 w0 = pw[0], w1 = pw[1];
            f16x8 bv;
            bv[0] = (f16)w0.x; bv[1] = (f16)w0.y; bv[2] = (f16)w0.z; bv[3] = (f16)w0.w;
            bv[4] = (f16)w1.x; bv[5] = (f16)w1.y; bv[6] = (f16)w1.z; bv[7] = (f16)w1.w;
            *(f16x8*)&Bs[sr * 40 + sq * 8] = bv;
        }
        __syncthreads();

        f16x8 af[2], bf[4];
#pragma unroll
        for (int mt = 0; mt < 2; mt++)
            af[mt] = *(const f16x8*)&As[(wm * 32 + mt * 16 + c) * 40 + g * 8];
#pragma unroll
        for (int nt = 0; nt < 4; nt++)
            bf[nt] = *(const f16x8*)&Bs[(wn * 64 + nt * 16 + c) * 40 + g * 8];
#pragma unroll
        for (int mt = 0; mt < 2; mt++)
#pragma unroll
            for (int nt = 0; nt < 4; nt++)
                acc[mt][nt] = __builtin_amdgcn_mfma_f32_16x16x32_f16(af[mt], bf[nt], acc[mt][nt], 0, 0, 0);
    }

#pragma unroll
    for (int mt = 0; mt < 2; mt++)
#pragma unroll
        for (int nt = 0; nt < 4; nt++) {
            int row0 = mBase + wm * 32 + mt * 16 + g * 4;
            int col = nBase + wn * 64 + nt * 16 + c;
            if (wsel == 2) {
                // Vp[bh][t][nd][c16][gv][4]
                int b = row0 >> 11, l0 = row0 & 2047;
                int h = col >> 6, dk = col & 63;
                int bh = b * 16 + h;
                int t = l0 >> 4, gv = (l0 & 15) >> 2;
                int nd = dk >> 4, c16 = dk & 15;
                f16x4 pv;
#pragma unroll
                for (int r = 0; r < 4; r++) pv[r] = (f16)acc[mt][nt][r];
                *(f16x4*)&Vp[(size_t)(bh * 128 + t) * 1024 + nd * 256 + c16 * 16 + gv * 4] = pv;
            } else {
                f16* Cp = wsel == 0 ? Qp : Kp;
                const float scale = wsel == 0 ? 0.0625f : 1.0f;   // 1/sqrt(64) * 1/2
#pragma unroll
                for (int r = 0; r < 4; r++) {
                    int row = row0 + r;
                    float v = acc[mt][nt][r] * scale;
                    int b = row >> 11, l = row & 2047;
                    int h = col >> 6, dk = col & 63;
                    int bh = b * 16 + h;
                    int t = l >> 4, ck = l & 15;
                    int half = dk >> 5, gk = (dk >> 3) & 3, e = dk & 7;
                    Cp[((size_t)(bh * 128 + t) * 2 + half) * 512 + ck * 32 + gk * 8 + e] = (f16)v;
                }
            }
        }
}

// ---------------------------------------------------------------------------
// out = AO @ Wo^T -> f32
// ---------------------------------------------------------------------------
__global__ __launch_bounds__(512)
void gemm_out(const f16* __restrict__ Ap, const float* __restrict__ Wp,
              float* __restrict__ Cp)
{
    __shared__ __align__(16) f16 As[128 * 40];
    __shared__ __align__(16) f16 Bs[128 * 40];

    const int tid = threadIdx.x;
    const int mBase = blockIdx.x * 128;
    const int nBase = blockIdx.y * 128;

    const int lane = tid & 63, w = tid >> 6;
    const int g = lane >> 4, c = lane & 15;
    const int wm = w >> 1, wn = w & 1;

    const int sr = tid >> 2;
    const int sq = tid & 3;

    f32x4 acc[2][4];
    const f32x4 vzero = {0.f, 0.f, 0.f, 0.f};
#pragma unroll
    for (int i = 0; i < 2; i++)
#pragma unroll
        for (int j = 0; j < 4; j++) acc[i][j] = vzero;

    for (int k0 = 0; k0 < 1024; k0 += 32) {
        __syncthreads();
        {
            *(f16x8*)&As[sr * 40 + sq * 8] =
                *(const f16x8*)&Ap[(size_t)(mBase + sr) * 1024 + k0 + sq * 8];

            const float4* pw = (const float4*)&Wp[(size_t)(nBase + sr) * 1024 + k0 + sq * 8];
            float4 w0 = pw[0], w1 = pw[1];
            f16x8 bv;
            bv[0] = (f16)w0.x; bv[1] = (f16)w0.y; bv[2] = (f16)w0.z; bv[3] = (f16)w0.w;
            bv[4] = (f16)w1.x; bv[5] = (f16)w1.y; bv[6] = (f16)w1.z; bv[7] = (f16)w1.w;
            *(f16x8*)&Bs[sr * 40 + sq * 8] = bv;
        }
        __syncthreads();

        f16x8 af[2], bf[4];
#pragma unroll
        for (int mt = 0; mt < 2; mt++)
            af[mt] = *(const f16x8*)&As[(wm * 32 + mt * 16 + c) * 40 + g * 8];
#pragma unroll
        for (int nt = 0; nt < 4; nt++)
            bf[nt] = *(const f16x8*)&Bs[(wn * 64 + nt * 16 + c) * 40 + g * 8];
#pragma unroll
        for (int mt = 0; mt < 2; mt++)
#pragma unroll
            for (int nt = 0; nt < 4; nt++)
                acc[mt][nt] = __builtin_amdgcn_mfma_f32_16x16x32_f16(af[mt], bf[nt], acc[mt][nt], 0, 0, 0);
    }

#pragma unroll
    for (int mt = 0; mt < 2; mt++)
#pragma unroll
        for (int nt = 0; nt < 4; nt++) {
            int row0 = mBase + wm * 32 + mt * 16 + g * 4;
            int col = nBase + wn * 64 + nt * 16 + c;
#pragma unroll
            for (int r = 0; r < 4; r++)
                Cp[(size_t)(row0 + r) * 1024 + col] = acc[mt][nt][r];
        }
}

// ---------------------------------------------------------------------------
// Attention + exact 1.5-entmax (coalesced loads, mask fast-path, packed VALU).
// ---------------------------------------------------------------------------
__global__ __launch_bounds__(512, 4)
void attn_entmax(const f16* __restrict__ Qp, const f16* __restrict__ Kp,
                 const f16* __restrict__ Vp, const u32* __restrict__ Mp,
                 f16* __restrict__ AO)
{
    constexpr int CAP = 512;
    constexpr int BSTR = 513;                        // padded row stride (f32)
    // Overlay: bucket f32[16][513] (32.8 KB) dies at taus barrier; Ored f32[8][16][68] after.
    __shared__ __align__(16) char LB[8 * 16 * 68 * 4];
    __shared__ int cntS[16];
    __shared__ float redM[8][16];
    __shared__ float redN[2][8][16][2];
    __shared__ float tau2s[16], zmaxs[16], taus[16];

    float* bucket = (float*)LB;
    float* Ored = (float*)LB;

    const int tid = threadIdx.x;
    const int w = tid >> 6, lane = tid & 63;
    const int g = lane >> 4, c = lane & 15;

    // XCD-aware swizzle: 4096 blocks = 8 XCD x (4 bh x 128 q-blocks)
    const int bid = blockIdx.x;
    const int q8 = bid >> 3;
    const int bh = (bid & 7) * 4 + (q8 >> 7);
    const int qt = q8 & 127;
    const int qb = qt * 16;
    const int b = bh >> 4, h = bh & 15;

    if (tid < 16) cntS[tid] = 0;

    // ---- Q B-fragments (coalesced: 1 KB per wave-instr) ----
    const f16* qbase = &Qp[(size_t)(bh * 128 + qt) * 1024 + c * 32 + g * 8];
    f16x8 bq0 = *(const f16x8*)qbase;
    f16x8 bq1 = *(const f16x8*)(qbase + 512);

    // ---- mask (coalesced: 512 B per wave-instr) ----
    const u32* mbase = &Mp[(((size_t)(b * 128 + qt) * 8 + w) << 7) + (c << 3)];
    uint4 mA = *(const uint4*)mbase;
    uint4 mB = *(const uint4*)(mbase + 4);
    u32 mb[8] = {mA.x, mA.y, mA.z, mA.w, mB.x, mB.y, mB.z, mB.w};

    // ---- scores: 4-tile chunks, double-buffered K ----
    f16x2 hS[32];
    f16x2 rmax; rmax.x = (f16)(-30000.f); rmax.y = (f16)(-30000.f);
    const f32x4 vz = {0.f, 0.f, 0.f, 0.f};
    const f16* kbaseP = &Kp[(size_t)(bh * 128 + w * 16) * 1024 + c * 32 + g * 8];

    f16x8 kb[2][8];
#pragma unroll
    for (int i = 0; i < 4; i++) {
        const f16* kp = kbaseP + (size_t)i * 1024;
        kb[0][2 * i]     = *(const f16x8*)kp;
        kb[0][2 * i + 1] = *(const f16x8*)(kp + 512);
    }
#pragma unroll
    for (int ch = 0; ch < 4; ch++) {
        if (ch < 3) {
#pragma unroll
            for (int i = 0; i < 4; i++) {
                const f16* kp = kbaseP + (size_t)((ch + 1) * 4 + i) * 1024;
                kb[(ch + 1) & 1][2 * i]     = *(const f16x8*)kp;
                kb[(ch + 1) & 1][2 * i + 1] = *(const f16x8*)(kp + 512);
            }
        }
#pragma unroll
        for (int i = 0; i < 4; i++) {
            const int t = ch * 4 + i;
            f32x4 z = __builtin_amdgcn_mfma_f32_16x16x32_f16(kb[ch & 1][2 * i], bq0, vz, 0, 0, 0);
            z = __builtin_amdgcn_mfma_f32_16x16x32_f16(kb[ch & 1][2 * i + 1], bq1, z, 0, 0, 0);
            u32 mw = mb[t >> 1];
            if (__builtin_expect(mw != 0xFFFFFFFFu, 0)) {   // mask fast-path
                u32 b4 = mw >> ((t & 1) * 16 + g * 4);
#pragma unroll
                for (int r = 0; r < 4; r++)
                    if (!((b4 >> r) & 1)) z[r] = -30000.f;
            }
            f16x2 p0 = pkrtz(z[0], z[1]);
            f16x2 p1 = pkrtz(z[2], z[3]);
            hS[2 * t] = p0;
            hS[2 * t + 1] = p1;
            rmax = max2(rmax, max2(p0, p1));
        }
    }

    // ---- zmax per query ----
    float zx = fmaxf((float)rmax.x, (float)rmax.y);
    zx = fmaxf(zx, __shfl_xor(zx, 16));
    zx = fmaxf(zx, __shfl_xor(zx, 32));
    if (lane < 16) redM[w][c] = zx;
    __syncthreads();
    float zmax = -3e38f;
#pragma unroll
    for (int ww = 0; ww < 8; ww++) zmax = fmaxf(zmax, redM[ww][c]);

    // ---- TWO cross-wave Newton iters from below (PACKED f16 scans) ----
    f16x2 zero2; zero2.x = (f16)0.f; zero2.y = (f16)0.f;
    float tau = zmax - 1.0f;
    int buf = 0;
#pragma unroll 1
    for (int it = 0; it < 2; ++it) {
        f16 tn = (f16)tau;
        f16x2 tv; tv.x = tn; tv.y = tn;
        f16x2 s1p = zero2, s2p = zero2;
#pragma unroll
        for (int i = 0; i < 32; i++) {
            f16x2 d = max2(hS[i] - tv, zero2);
            s1p = s1p + d;
            s2p = s2p + d * d;
        }
        s1p = s1p + shfl2(s1p, 16);
        s2p = s2p + shfl2(s2p, 16);
        s1p = s1p + shfl2(s1p, 32);
        s2p = s2p + shfl2(s2p, 32);
        float s1 = (float)s1p.x + (float)s1p.y;
        float s2 = (float)s2p.x + (float)s2p.y;
        if (lane < 16) { redN[buf][w][c][0] = s1; redN[buf][w][c][1] = s2; }
        __syncthreads();
        float a = 0.f, f = 0.f;
#pragma unroll
        for (int ww = 0; ww < 8; ww++) {
            float2 v2 = *(const float2*)&redN[buf][ww][c][0];
            a += v2.x; f += v2.y;
        }
        if (a > 1e-9f)
            tau = fminf(tau + (f - 1.0f) / (2.0f * a), zmax - 1e-3f);
        buf ^= 1;
    }
    if (w == 0 && lane < 16) { tau2s[c] = tau; zmaxs[c] = zmax; }

    // ---- filter survivors: packed sign-bit fast test, 0.02 margin ----
    const f16 thrh = (f16)(tau - 0.02f);
    f16x2 thr2; thr2.x = thrh; thr2.y = thrh;
#pragma unroll
    for (int i = 0; i < 32; i++) {
        union { f16x2 h; u32 u; } dd;
        dd.h = hS[i] - thr2;
        u32 pos = ~dd.u & 0x80008000u;     // nonzero iff either half >= thr
        if (__builtin_expect(pos != 0, 0)) {
            if (hS[i].x > thrh) { int id = atomicAdd(&cntS[c], 1); if (id < CAP) bucket[c * BSTR + id] = (float)hS[i].x; }
            if (hS[i].y > thrh) { int id = atomicAdd(&cntS[c], 1); if (id < CAP) bucket[c * BSTR + id] = (float)hS[i].y; }
        }
    }
    __syncthreads();

    // ---- bucket solve: quarter-wave per query (4 queries / wave), f32 ----
    {
        const int qi = 4 * w + (lane >> 4);
        const int sl = lane & 15;
        const int cnt = min(cntS[qi], CAP);
        const int ns = (cnt + 15) >> 4;
        float tq = tau2s[qi];
        const float zq = zmaxs[qi];
#pragma unroll 1
        for (int it = 0; it < 4; ++it) {
            float s1 = 0.f, s2 = 0.f;
#pragma unroll 1
            for (int s = 0; s < ns; s++) {
                int i = sl + 16 * s;
                float v = (i < cnt) ? bucket[qi * BSTR + i] : -1e30f;
                float d = fmaxf(v - tq, 0.f);
                s1 += d; s2 = fmaf(d, d, s2);
            }
#pragma unroll
            for (int off = 1; off <= 8; off <<= 1) {
                s1 += __shfl_xor(s1, off);
                s2 += __shfl_xor(s2, off);
            }
            if (s1 > 1e-12f) tq = fminf(tq + (s2 - 1.0f) / (2.0f * s1), zq - 1e-3f);
        }
#pragma unroll 1
        for (int rf = 0; rf < 3; ++rf) {
            float kc = 0.f, s1 = 0.f, s2 = 0.f;
#pragma unroll 1
            for (int s = 0; s < ns; s++) {
                int i = sl + 16 * s;
                float v = (i < cnt) ? bucket[qi * BSTR + i] : -1e30f;
                float d = v - tq;
                if (d > 0.f) { kc += 1.f; s1 += d; s2 = fmaf(d, d, s2); }
            }
#pragma unroll
            for (int off = 1; off <= 8; off <<= 1) {
                kc += __shfl_xor(kc, off);
                s1 += __shfl_xor(s1, off);
                s2 += __shfl_xor(s2, off);
            }
            float K_ = fmaxf(kc, 1.0f);
            float disc = fmaxf(s1 * s1 - K_ * (s2 - 1.0f), 0.f);
            tq += (s1 - sqrtf(disc)) / K_;
        }
        if (sl == 0) taus[qi] = tq;
    }
    __syncthreads();     // taus ready; bucket dead -> LB becomes Ored

    // ---- P packed + PV (coalesced Vp loads) ----
    const f16 tch = (f16)taus[c];
    f16x2 tv2; tv2.x = tch; tv2.y = tch;
    f32x4 O[4];
#pragma unroll
    for (int nd = 0; nd < 4; nd++) O[nd] = vz;
    const f16* vbase = &Vp[(size_t)(bh * 128 + w * 16) * 1024 + c * 16 + g * 4];
#pragma unroll
    for (int t = 0; t < 16; t++) {
        f16x2 da = max2(hS[2 * t] - tv2, zero2);
        f16x2 db = max2(hS[2 * t + 1] - tv2, zero2);
        da = da * da;
        db = db * db;
        union { f16x4 v4; f16x2 h2[2]; } pu;
        pu.h2[0] = da; pu.h2[1] = db;
        const f16* vp = vbase + (size_t)t * 1024;
#pragma unroll
        for (int nd = 0; nd < 4; nd++) {
            f16x4 va = *(const f16x4*)(vp + nd * 256);
            O[nd] = __builtin_amdgcn_mfma_f32_16x16x16f16(va, pu.v4, O[nd], 0, 0, 0);
        }
    }

    // ---- cross-wave O reduction (Ored overlays bucket) ----
#pragma unroll
    for (int nd = 0; nd < 4; nd++)
        *(f32x4*)&Ored[(w * 16 + c) * 68 + nd * 16 + g * 4] = O[nd];
    __syncthreads();

    const int qrow = tid >> 5;
    const int dp = tid & 31;
    float o0 = 0.f, o1 = 0.f;
#pragma unroll
    for (int ww = 0; ww < 8; ww++) {
        float2 v = *(const float2*)&Ored[(ww * 16 + qrow) * 68 + dp * 2];
        o0 += v.x; o1 += v.y;
    }
    f16x2 pk = pkrtz(o0, o1);
    *(f16x2*)&AO[(size_t)(b * 2048 + qb + qrow) * 1024 + h * 64 + dp * 2] = pk;
}

// ---------------------------------------------------------------------------
extern "C" void kernel_launch(void* const* d_in, const int* in_sizes, int n_in,
                              void* d_out, int out_size, void* d_ws, size_t ws_size,
                              hipStream_t stream)
{
    const float* q  = (const float*)d_in[0];
    const float* k  = (const float*)d_in[1];
    const float* v  = (const float*)d_in[2];
    const int* mask = (const int*)d_in[3];
    const float* wq = (const float*)d_in[4];
    const float* wk = (const float*)d_in[5];
    const float* wv = (const float*)d_in[6];
    const float* wo = (const float*)d_in[7];

    char* ws = (char*)d_ws;
    const size_t SZ = 8388608ull;            // 8 MB per f16 buffer
    f16* Qb  = (f16*)(ws);
    f16* Kb  = (f16*)(ws + SZ);
    f16* Vb  = (f16*)(ws + 2 * SZ);
    f16* AOb = (f16*)(ws + 3 * SZ);
    u32* Mb  = (u32*)(ws + 4 * SZ);          // 1 MB packed mask

    pack_mask<<<1024, 256, 0, stream>>>(mask, Mb);
    gemm_qkv<<<dim3(32, 24), 512, 0, stream>>>(q, k, v, wq, wk, wv, Qb, Kb, Vb);
    attn_entmax<<<4096, 512, 0, stream>>>(Qb, Kb, Vb, Mb, AOb);
    gemm_out<<<dim3(32, 8), 512, 0, stream>>>(AOb, wo, (float*)d_out);
}

// Round 16
// 336.191 us; speedup vs baseline: 1.2752x; 1.1193x over previous
//
#include <hip/hip_runtime.h>

// Shapes: B=2, L=2048, D_MODEL=1024, H=16, D_K=64
// Pipeline (R16 = R15 attn widened to 32 queries/block @ launch_bounds(512,2)):
//  0) pack_mask: mask int32 [B][L][L] -> Mp[b][qt16][w][c][8] u32.
//  1) gemm_qkv: fused Q/K/V projections (wsel = by>>3); FRAGMENT-PACKED outputs.
//  2) attn_entmax: 32 q x 2048 k per block, 8 waves, XCD-swizzled grid.
//     Two q-tiles (A,B) share every K and V fragment -> half the L2 traffic,
//     half the barriers per query. Swapped QK^T -> f16x2 scores in regs;
//     TWO cross-wave Newton iters (packed f16), filter at tau2-0.02 into f32
//     buckets (CAP=512/query), quarter-wave f32 solve (4 Newton + 3 exact
//     support refines), P packed f16 -> PV from regs.
//  3) gemm_out: out = AO @ Wo^T -> f32 d_out.

typedef _Float16 f16;
typedef __attribute__((ext_vector_type(8))) _Float16 f16x8;
typedef __attribute__((ext_vector_type(4))) _Float16 f16x4;
typedef __attribute__((ext_vector_type(2))) _Float16 f16x2;
typedef __attribute__((ext_vector_type(4))) float f32x4;
typedef unsigned int u32;

static __device__ __forceinline__ f16x2 max2(f16x2 a, f16x2 b) {
    return __builtin_elementwise_max(a, b);
}

static __device__ __forceinline__ f16x2 shfl2(f16x2 v, int off) {
    union { f16x2 h; int i; } u;
    u.h = v;
    u.i = __shfl_xor(u.i, off);
    return u.h;
}

static __device__ __forceinline__ f16x2 pkrtz(float a, float b) {
    union { __fp16 __attribute__((ext_vector_type(2))) p; f16x2 h; } u;
    u.p = __builtin_amdgcn_cvt_pkrtz(a, b);
    return u.h;
}

// ---------------------------------------------------------------------------
// mask [2][2048][2048] int -> Mp[b][qt16=128][w=8][c=16][8] u32
// ---------------------------------------------------------------------------
__global__ __launch_bounds__(256)
void pack_mask(const int* __restrict__ mask, u32* __restrict__ bits)
{
    int idx = blockIdx.x * 256 + threadIdx.x;        // (b*2048+q)*64 + wd
    const int4* p = (const int4*)&mask[(size_t)idx * 32];
    u32 v = 0;
#pragma unroll
    for (int i = 0; i < 8; i++) {
        int4 m = p[i];
        if (m.x != 0) v |= 1u << (i * 4 + 0);
        if (m.y != 0) v |= 1u << (i * 4 + 1);
        if (m.z != 0) v |= 1u << (i * 4 + 2);
        if (m.w != 0) v |= 1u << (i * 4 + 3);
    }
    const int wd = idx & 63;
    const int q = (idx >> 6) & 2047;
    const int b = idx >> 17;
    bits[(((size_t)(b * 128 + (q >> 4)) * 8 + (wd >> 3)) << 7) + ((q & 15) << 3) + (wd & 7)] = v;
}

// ---------------------------------------------------------------------------
// Fused Q/K/V projection: C = A @ W^T, wsel = by>>3 picks (A, W, epilogue).
// ---------------------------------------------------------------------------
__global__ __launch_bounds__(512)
void gemm_qkv(const float* __restrict__ Aq, const float* __restrict__ Ak,
              const float* __restrict__ Av, const float* __restrict__ W0,
              const float* __restrict__ W1, const float* __restrict__ W2,
              f16* __restrict__ Qp, f16* __restrict__ Kp, f16* __restrict__ Vp)
{
    __shared__ __align__(16) f16 As[128 * 40];
    __shared__ __align__(16) f16 Bs[128 * 40];

    const int tid = threadIdx.x;
    const int wsel = blockIdx.y >> 3;
    const float* A  = wsel == 0 ? Aq : (wsel == 1 ? Ak : Av);
    const float* Wp = wsel == 0 ? W0 : (wsel == 1 ? W1 : W2);
    const int mBase = blockIdx.x * 128;
    const int nBase = (blockIdx.y & 7) * 128;

    const int lane = tid & 63, w = tid >> 6;
    const int g = lane >> 4, c = lane & 15;
    const int wm = w >> 1, wn = w & 1;

    const int sr = tid >> 2;
    const int sq = tid & 3;

    f32x4 acc[2][4];
    const f32x4 vzero = {0.f, 0.f, 0.f, 0.f};
#pragma unroll
    for (int i = 0; i < 2; i++)
#pragma unroll
        for (int j = 0; j < 4; j++) acc[i][j] = vzero;

    for (int k0 = 0; k0 < 1024; k0 += 32) {
        __syncthreads();
        {
            const float4* p = (const float4*)&A[(size_t)(mBase + sr) * 1024 + k0 + sq * 8];
            float4 x0 = p[0], x1 = p[1];
            f16x8 av;
            av[0] = (f16)x0.x; av[1] = (f16)x0.y; av[2] = (f16)x0.z; av[3] = (f16)x0.w;
            av[4] = (f16)x1.x; av[5] = (f16)x1.y; av[6] = (f16)x1.z; av[7] = (f16)x1.w;
            *(f16x8*)&As[sr * 40 + sq * 8] = av;

            const float4* pw = (const float4*)&Wp[(size_t)(nBase + sr) * 1024 + k0 + sq * 8];
            float4 w0 = pw[0], w1 = pw[1];
            f16x8 bv;
            bv[0] = (f16)w0.x; bv[1] = (f16)w0.y; bv[2] = (f16)w0.z; bv[3] = (f16)w0.w;
            bv[4] = (f16)w1.x; bv[5] = (f16)w1.y; bv[6] = (f16)w1.z; bv[7] = (f16)w1.w;
            *(f16x8*)&Bs[sr * 40 + sq * 8] = bv;
        }
        __syncthreads();

        f16x8 af[2], bf[4];
#pragma unroll
        for (int mt = 0; mt < 2; mt++)
            af[mt] = *(const f16x8*)&As[(wm * 32 + mt * 16 + c) * 40 + g * 8];
#pragma unroll
        for (int nt = 0; nt < 4; nt++)
            bf[nt] = *(const f16x8*)&Bs[(wn * 64 + nt * 16 + c) * 40 + g * 8];
#pragma unroll
        for (int mt = 0; mt < 2; mt++)
#pragma unroll
            for (int nt = 0; nt < 4; nt++)
                acc[mt][nt] = __builtin_amdgcn_mfma_f32_16x16x32_f16(af[mt], bf[nt], acc[mt][nt], 0, 0, 0);
    }

#pragma unroll
    for (int mt = 0; mt < 2; mt++)
#pragma unroll
        for (int nt = 0; nt < 4; nt++) {
            int row0 = mBase + wm * 32 + mt * 16 + g * 4;
            int col = nBase + wn * 64 + nt * 16 + c;
            if (wsel == 2) {
                int b = row0 >> 11, l0 = row0 & 2047;
                int h = col >> 6, dk = col & 63;
                int bh = b * 16 + h;
                int t = l0 >> 4, gv = (l0 & 15) >> 2;
                int nd = dk >> 4, c16 = dk & 15;
                f16x4 pv;
#pragma unroll
                for (int r = 0; r < 4; r++) pv[r] = (f16)acc[mt][nt][r];
                *(f16x4*)&Vp[(size_t)(bh * 128 + t) * 1024 + nd * 256 + c16 * 16 + gv * 4] = pv;
            } else {
                f16* Cp = wsel == 0 ? Qp : Kp;
                const float scale = wsel == 0 ? 0.0625f : 1.0f;   // 1/sqrt(64) * 1/2
#pragma unroll
                for (int r = 0; r < 4; r++) {
                    int row = row0 + r;
                    float v = acc[mt][nt][r] * scale;
                    int b = row >> 11, l = row & 2047;
                    int h = col >> 6, dk = col & 63;
                    int bh = b * 16 + h;
                    int t = l >> 4, ck = l & 15;
                    int half = dk >> 5, gk = (dk >> 3) & 3, e = dk & 7;
                    Cp[((size_t)(bh * 128 + t) * 2 + half) * 512 + ck * 32 + gk * 8 + e] = (f16)v;
                }
            }
        }
}

// ---------------------------------------------------------------------------
// out = AO @ Wo^T -> f32
// ---------------------------------------------------------------------------
__global__ __launch_bounds__(512)
void gemm_out(const f16* __restrict__ Ap, const float* __restrict__ Wp,
              float* __restrict__ Cp)
{
    __shared__ __align__(16) f16 As[128 * 40];
    __shared__ __align__(16) f16 Bs[128 * 40];

    const int tid = threadIdx.x;
    const int mBase = blockIdx.x * 128;
    const int nBase = blockIdx.y * 128;

    const int lane = tid & 63, w = tid >> 6;
    const int g = lane >> 4, c = lane & 15;
    const int wm = w >> 1, wn = w & 1;

    const int sr = tid >> 2;
    const int sq = tid & 3;

    f32x4 acc[2][4];
    const f32x4 vzero = {0.f, 0.f, 0.f, 0.f};
#pragma unroll
    for (int i = 0; i < 2; i++)
#pragma unroll
        for (int j = 0; j < 4; j++) acc[i][j] = vzero;

    for (int k0 = 0; k0 < 1024; k0 += 32) {
        __syncthreads();
        {
            *(f16x8*)&As[sr * 40 + sq * 8] =
                *(const f16x8*)&Ap[(size_t)(mBase + sr) * 1024 + k0 + sq * 8];

            const float4* pw = (const float4*)&Wp[(size_t)(nBase + sr) * 1024 + k0 + sq * 8];
            float4 w0 = pw[0], w1 = pw[1];
            f16x8 bv;
            bv[0] = (f16)w0.x; bv[1] = (f16)w0.y; bv[2] = (f16)w0.z; bv[3] = (f16)w0.w;
            bv[4] = (f16)w1.x; bv[5] = (f16)w1.y; bv[6] = (f16)w1.z; bv[7] = (f16)w1.w;
            *(f16x8*)&Bs[sr * 40 + sq * 8] = bv;
        }
        __syncthreads();

        f16x8 af[2], bf[4];
#pragma unroll
        for (int mt = 0; mt < 2; mt++)
            af[mt] = *(const f16x8*)&As[(wm * 32 + mt * 16 + c) * 40 + g * 8];
#pragma unroll
        for (int nt = 0; nt < 4; nt++)
            bf[nt] = *(const f16x8*)&Bs[(wn * 64 + nt * 16 + c) * 40 + g * 8];
#pragma unroll
        for (int mt = 0; mt < 2; mt++)
#pragma unroll
            for (int nt = 0; nt < 4; nt++)
                acc[mt][nt] = __builtin_amdgcn_mfma_f32_16x16x32_f16(af[mt], bf[nt], acc[mt][nt], 0, 0, 0);
    }

#pragma unroll
    for (int mt = 0; mt < 2; mt++)
#pragma unroll
        for (int nt = 0; nt < 4; nt++) {
            int row0 = mBase + wm * 32 + mt * 16 + g * 4;
            int col = nBase + wn * 64 + nt * 16 + c;
#pragma unroll
            for (int r = 0; r < 4; r++)
                Cp[(size_t)(row0 + r) * 1024 + col] = acc[mt][nt][r];
        }
}

// ---------------------------------------------------------------------------
// Attention + exact 1.5-entmax; 32 queries/block, K/V shared by 2 q-tiles.
// ---------------------------------------------------------------------------
__global__ __launch_bounds__(512, 2)
void attn_entmax(const f16* __restrict__ Qp, const f16* __restrict__ Kp,
                 const f16* __restrict__ Vp, const u32* __restrict__ Mp,
                 f16* __restrict__ AO)
{
    constexpr int CAP = 512;
    constexpr int BSTR = 513;
    // Overlay: bucket f32[32][513] (65.7 KB) dies at taus barrier; Ored f32[8][32][68] (69.6 KB) after.
    __shared__ __align__(16) char LB[8 * 32 * 68 * 4];
    __shared__ int cntS[32];
    __shared__ float redM[8][32];
    __shared__ float redN[2][8][32][2];
    __shared__ float tau2s[32], zmaxs[32], taus[32];

    float* bucket = (float*)LB;
    float* Ored = (float*)LB;

    const int tid = threadIdx.x;
    const int w = tid >> 6, lane = tid & 63;
    const int g = lane >> 4, c = lane & 15;

    // XCD-aware swizzle: 2048 blocks = 8 XCD x (4 bh x 64 q-blocks)
    const int bid = blockIdx.x;
    const int q6 = bid >> 3;
    const int bh = (bid & 7) * 4 + (q6 >> 6);
    const int qt = q6 & 63;                  // 32-query tile
    const int qb = qt * 32;
    const int b = bh >> 4, h = bh & 15;

    if (tid < 32) cntS[tid] = 0;

    // ---- Q B-fragments for both q-tiles ----
    const f16* qbaseA = &Qp[(size_t)(bh * 128 + 2 * qt) * 1024 + c * 32 + g * 8];
    f16x8 bqA0 = *(const f16x8*)qbaseA;
    f16x8 bqA1 = *(const f16x8*)(qbaseA + 512);
    f16x8 bqB0 = *(const f16x8*)(qbaseA + 1024);
    f16x8 bqB1 = *(const f16x8*)(qbaseA + 1536);

    // ---- masks for both q-tiles ----
    const u32* mbaseA = &Mp[(((size_t)(b * 128 + 2 * qt) * 8 + w) << 7) + (c << 3)];
    uint4 mA0 = *(const uint4*)mbaseA;
    uint4 mA1 = *(const uint4*)(mbaseA + 4);
    uint4 mB0 = *(const uint4*)(mbaseA + 128);
    uint4 mB1 = *(const uint4*)(mbaseA + 132);
    u32 mbA[8] = {mA0.x, mA0.y, mA0.z, mA0.w, mA1.x, mA1.y, mA1.z, mA1.w};
    u32 mbB[8] = {mB0.x, mB0.y, mB0.z, mB0.w, mB1.x, mB1.y, mB1.z, mB1.w};

    // ---- scores: each K fragment feeds BOTH q-tiles (4 MFMAs / 2 loads) ----
    f16x2 hSA[32], hSB[32];
    f16x2 rmaxA; rmaxA.x = (f16)(-30000.f); rmaxA.y = (f16)(-30000.f);
    f16x2 rmaxB = rmaxA;
    const f32x4 vz = {0.f, 0.f, 0.f, 0.f};
    const f16* kbaseP = &Kp[(size_t)(bh * 128 + w * 16) * 1024 + c * 32 + g * 8];
#pragma unroll
    for (int t = 0; t < 16; t++) {
        const f16* kp = kbaseP + (size_t)t * 1024;
        f16x8 ka0 = *(const f16x8*)kp;
        f16x8 ka1 = *(const f16x8*)(kp + 512);
        f32x4 zA = __builtin_amdgcn_mfma_f32_16x16x32_f16(ka0, bqA0, vz, 0, 0, 0);
        zA = __builtin_amdgcn_mfma_f32_16x16x32_f16(ka1, bqA1, zA, 0, 0, 0);
        f32x4 zB = __builtin_amdgcn_mfma_f32_16x16x32_f16(ka0, bqB0, vz, 0, 0, 0);
        zB = __builtin_amdgcn_mfma_f32_16x16x32_f16(ka1, bqB1, zB, 0, 0, 0);
        u32 mwA = mbA[t >> 1], mwB = mbB[t >> 1];
        if (__builtin_expect(mwA != 0xFFFFFFFFu, 0)) {
            u32 b4 = mwA >> ((t & 1) * 16 + g * 4);
#pragma unroll
            for (int r = 0; r < 4; r++)
                if (!((b4 >> r) & 1)) zA[r] = -30000.f;
        }
        if (__builtin_expect(mwB != 0xFFFFFFFFu, 0)) {
            u32 b4 = mwB >> ((t & 1) * 16 + g * 4);
#pragma unroll
            for (int r = 0; r < 4; r++)
                if (!((b4 >> r) & 1)) zB[r] = -30000.f;
        }
        f16x2 a0 = pkrtz(zA[0], zA[1]), a1 = pkrtz(zA[2], zA[3]);
        f16x2 b0 = pkrtz(zB[0], zB[1]), b1 = pkrtz(zB[2], zB[3]);
        hSA[2 * t] = a0; hSA[2 * t + 1] = a1;
        hSB[2 * t] = b0; hSB[2 * t + 1] = b1;
        rmaxA = max2(rmaxA, max2(a0, a1));
        rmaxB = max2(rmaxB, max2(b0, b1));
    }

    // ---- zmax per query ----
    float zxA = fmaxf((float)rmaxA.x, (float)rmaxA.y);
    float zxB = fmaxf((float)rmaxB.x, (float)rmaxB.y);
    zxA = fmaxf(zxA, __shfl_xor(zxA, 16)); zxA = fmaxf(zxA, __shfl_xor(zxA, 32));
    zxB = fmaxf(zxB, __shfl_xor(zxB, 16)); zxB = fmaxf(zxB, __shfl_xor(zxB, 32));
    if (lane < 16) { redM[w][c] = zxA; redM[w][16 + c] = zxB; }
    __syncthreads();
    float zmaxA = -3e38f, zmaxB = -3e38f;
#pragma unroll
    for (int ww = 0; ww < 8; ww++) {
        zmaxA = fmaxf(zmaxA, redM[ww][c]);
        zmaxB = fmaxf(zmaxB, redM[ww][16 + c]);
    }

    // ---- TWO cross-wave Newton iters from below (packed f16 scans) ----
    f16x2 zero2; zero2.x = (f16)0.f; zero2.y = (f16)0.f;
    float tauA = zmaxA - 1.0f, tauB = zmaxB - 1.0f;
    int buf = 0;
#pragma unroll 1
    for (int it = 0; it < 2; ++it) {
        f16 tnA = (f16)tauA, tnB = (f16)tauB;
        f16x2 tvA; tvA.x = tnA; tvA.y = tnA;
        f16x2 tvB; tvB.x = tnB; tvB.y = tnB;
        f16x2 s1A = zero2, s2A = zero2, s1B = zero2, s2B = zero2;
#pragma unroll
        for (int i = 0; i < 32; i++) {
            f16x2 dA = max2(hSA[i] - tvA, zero2);
            f16x2 dB = max2(hSB[i] - tvB, zero2);
            s1A = s1A + dA; s2A = s2A + dA * dA;
            s1B = s1B + dB; s2B = s2B + dB * dB;
        }
        s1A = s1A + shfl2(s1A, 16); s2A = s2A + shfl2(s2A, 16);
        s1A = s1A + shfl2(s1A, 32); s2A = s2A + shfl2(s2A, 32);
        s1B = s1B + shfl2(s1B, 16); s2B = s2B + shfl2(s2B, 16);
        s1B = s1B + shfl2(s1B, 32); s2B = s2B + shfl2(s2B, 32);
        float a1 = (float)s1A.x + (float)s1A.y;
        float f1 = (float)s2A.x + (float)s2A.y;
        float a2 = (float)s1B.x + (float)s1B.y;
        float f2 = (float)s2B.x + (float)s2B.y;
        if (lane < 16) {
            redN[buf][w][c][0] = a1; redN[buf][w][c][1] = f1;
            redN[buf][w][16 + c][0] = a2; redN[buf][w][16 + c][1] = f2;
        }
        __syncthreads();
        float aA = 0.f, fA = 0.f, aB = 0.f, fB = 0.f;
#pragma unroll
        for (int ww = 0; ww < 8; ww++) {
            float2 vA = *(const float2*)&redN[buf][ww][c][0];
            float2 vB = *(const float2*)&redN[buf][ww][16 + c][0];
            aA += vA.x; fA += vA.y;
            aB += vB.x; fB += vB.y;
        }
        if (aA > 1e-9f) tauA = fminf(tauA + (fA - 1.0f) / (2.0f * aA), zmaxA - 1e-3f);
        if (aB > 1e-9f) tauB = fminf(tauB + (fB - 1.0f) / (2.0f * aB), zmaxB - 1e-3f);
        buf ^= 1;
    }
    if (w == 0 && lane < 16) {
        tau2s[c] = tauA; tau2s[16 + c] = tauB;
        zmaxs[c] = zmaxA; zmaxs[16 + c] = zmaxB;
    }

    // ---- filter survivors (packed sign-bit fast test, 0.02 margin) ----
    const f16 thrA = (f16)(tauA - 0.02f);
    const f16 thrB = (f16)(tauB - 0.02f);
    f16x2 thrA2; thrA2.x = thrA; thrA2.y = thrA;
    f16x2 thrB2; thrB2.x = thrB; thrB2.y = thrB;
#pragma unroll
    for (int i = 0; i < 32; i++) {
        union { f16x2 h; u32 u; } dA, dB;
        dA.h = hSA[i] - thrA2;
        dB.h = hSB[i] - thrB2;
        u32 posA = ~dA.u & 0x80008000u;
        u32 posB = ~dB.u & 0x80008000u;
        if (__builtin_expect(posA != 0, 0)) {
            if (hSA[i].x > thrA) { int id = atomicAdd(&cntS[c], 1); if (id < CAP) bucket[c * BSTR + id] = (float)hSA[i].x; }
            if (hSA[i].y > thrA) { int id = atomicAdd(&cntS[c], 1); if (id < CAP) bucket[c * BSTR + id] = (float)hSA[i].y; }
        }
        if (__builtin_expect(posB != 0, 0)) {
            if (hSB[i].x > thrB) { int id = atomicAdd(&cntS[16 + c], 1); if (id < CAP) bucket[(16 + c) * BSTR + id] = (float)hSB[i].x; }
            if (hSB[i].y > thrB) { int id = atomicAdd(&cntS[16 + c], 1); if (id < CAP) bucket[(16 + c) * BSTR + id] = (float)hSB[i].y; }
        }
    }
    __syncthreads();

    // ---- bucket solve: quarter-wave per query (4 queries / wave), f32 ----
    {
        const int qi = 4 * w + (lane >> 4);      // 0..31
        const int sl = lane & 15;
        const int cnt = min(cntS[qi], CAP);
        const int ns = (cnt + 15) >> 4;
        float tq = tau2s[qi];
        const float zq = zmaxs[qi];
#pragma unroll 1
        for (int it = 0; it < 4; ++it) {
            float s1 = 0.f, s2 = 0.f;
#pragma unroll 1
            for (int s = 0; s < ns; s++) {
                int i = sl + 16 * s;
                float v = (i < cnt) ? bucket[qi * BSTR + i] : -1e30f;
                float d = fmaxf(v - tq, 0.f);
                s1 += d; s2 = fmaf(d, d, s2);
            }
#pragma unroll
            for (int off = 1; off <= 8; off <<= 1) {
                s1 += __shfl_xor(s1, off);
                s2 += __shfl_xor(s2, off);
            }
            if (s1 > 1e-12f) tq = fminf(tq + (s2 - 1.0f) / (2.0f * s1), zq - 1e-3f);
        }
#pragma unroll 1
        for (int rf = 0; rf < 3; ++rf) {
            float kc = 0.f, s1 = 0.f, s2 = 0.f;
#pragma unroll 1
            for (int s = 0; s < ns; s++) {
                int i = sl + 16 * s;
                float v = (i < cnt) ? bucket[qi * BSTR + i] : -1e30f;
                float d = v - tq;
                if (d > 0.f) { kc += 1.f; s1 += d; s2 = fmaf(d, d, s2); }
            }
#pragma unroll
            for (int off = 1; off <= 8; off <<= 1) {
                kc += __shfl_xor(kc, off);
                s1 += __shfl_xor(s1, off);
                s2 += __shfl_xor(s2, off);
            }
            float K_ = fmaxf(kc, 1.0f);
            float disc = fmaxf(s1 * s1 - K_ * (s2 - 1.0f), 0.f);
            tq += (s1 - sqrtf(disc)) / K_;
        }
        if (sl == 0) taus[qi] = tq;
    }
    __syncthreads();     // taus ready; bucket dead -> LB becomes Ored

    // ---- P packed + PV: each V fragment feeds BOTH q-tiles ----
    const f16 tcA = (f16)taus[c];
    const f16 tcB = (f16)taus[16 + c];
    f16x2 tvA2; tvA2.x = tcA; tvA2.y = tcA;
    f16x2 tvB2; tvB2.x = tcB; tvB2.y = tcB;
    f32x4 O0[4], O1[4];
#pragma unroll
    for (int nd = 0; nd < 4; nd++) { O0[nd] = vz; O1[nd] = vz; }
    const f16* vbase = &Vp[(size_t)(bh * 128 + w * 16) * 1024 + c * 16 + g * 4];
#pragma unroll
    for (int t = 0; t < 16; t++) {
        f16x2 daA = max2(hSA[2 * t] - tvA2, zero2);
        f16x2 dbA = max2(hSA[2 * t + 1] - tvA2, zero2);
        f16x2 daB = max2(hSB[2 * t] - tvB2, zero2);
        f16x2 dbB = max2(hSB[2 * t + 1] - tvB2, zero2);
        daA = daA * daA; dbA = dbA * dbA;
        daB = daB * daB; dbB = dbB * dbB;
        union { f16x4 v4; f16x2 h2[2]; } puA, puB;
        puA.h2[0] = daA; puA.h2[1] = dbA;
        puB.h2[0] = daB; puB.h2[1] = dbB;
        const f16* vp = vbase + (size_t)t * 1024;
#pragma unroll
        for (int nd = 0; nd < 4; nd++) {
            f16x4 va = *(const f16x4*)(vp + nd * 256);
            O0[nd] = __builtin_amdgcn_mfma_f32_16x16x16f16(va, puA.v4, O0[nd], 0, 0, 0);
            O1[nd] = __builtin_amdgcn_mfma_f32_16x16x16f16(va, puB.v4, O1[nd], 0, 0, 0);
        }
    }

    // ---- cross-wave O reduction (Ored overlays bucket) ----
#pragma unroll
    for (int nd = 0; nd < 4; nd++) {
        *(f32x4*)&Ored[(w * 32 + c) * 68 + nd * 16 + g * 4] = O0[nd];
        *(f32x4*)&Ored[(w * 32 + 16 + c) * 68 + nd * 16 + g * 4] = O1[nd];
    }
    __syncthreads();

    const int qr = tid >> 4;          // 0..31
    const int d0 = (tid & 15) * 4;    // 0..60
    float4 accv = {0.f, 0.f, 0.f, 0.f};
#pragma unroll
    for (int ww = 0; ww < 8; ww++) {
        float4 v = *(const float4*)&Ored[(ww * 32 + qr) * 68 + d0];
        accv.x += v.x; accv.y += v.y; accv.z += v.z; accv.w += v.w;
    }
    f16x4 pk;
    pk[0] = (f16)accv.x; pk[1] = (f16)accv.y; pk[2] = (f16)accv.z; pk[3] = (f16)accv.w;
    *(f16x4*)&AO[(size_t)(b * 2048 + qb + qr) * 1024 + h * 64 + d0] = pk;
}

// ---------------------------------------------------------------------------
extern "C" void kernel_launch(void* const* d_in, const int* in_sizes, int n_in,
                              void* d_out, int out_size, void* d_ws, size_t ws_size,
                              hipStream_t stream)
{
    const float* q  = (const float*)d_in[0];
    const float* k  = (const float*)d_in[1];
    const float* v  = (const float*)d_in[2];
    const int* mask = (const int*)d_in[3];
    const float* wq = (const float*)d_in[4];
    const float* wk = (const float*)d_in[5];
    const float* wv = (const float*)d_in[6];
    const float* wo = (const float*)d_in[7];

    char* ws = (char*)d_ws;
    const size_t SZ = 8388608ull;            // 8 MB per f16 buffer
    f16* Qb  = (f16*)(ws);
    f16* Kb  = (f16*)(ws + SZ);
    f16* Vb  = (f16*)(ws + 2 * SZ);
    f16* AOb = (f16*)(ws + 3 * SZ);
    u32* Mb  = (u32*)(ws + 4 * SZ);          // 1 MB packed mask

    pack_mask<<<1024, 256, 0, stream>>>(mask, Mb);
    gemm_qkv<<<dim3(32, 24), 512, 0, stream>>>(q, k, v, wq, wk, wv, Qb, Kb, Vb);
    attn_entmax<<<2048, 512, 0, stream>>>(Qb, Kb, Vb, Mb, AOb);
    gemm_out<<<dim3(32, 8), 512, 0, stream>>>(AOb, wo, (float*)d_out);
}